// Round 1
// baseline (494.827 us; speedup 1.0000x reference)
//
#include <hip/hip_runtime.h>
#include <hip/hip_bf16.h>

#define B_ 32
#define F_ 4096
#define H_ 32
#define D_ 128
#define L_ 8192
#define CL 256            // attention chunk length
#define NKC 32            // k-chunks for the two big projections (F_/128)
#define NCH 32            // L_/CL
#define SCALE 0.08838834764831845f
#define LOG2E 1.4426950408889634f

typedef __attribute__((ext_vector_type(8))) short bf16x8;
typedef __attribute__((ext_vector_type(4))) short short4v;
typedef __attribute__((ext_vector_type(4))) float f32x4;

static __device__ __forceinline__ unsigned short f2bf(float f) {
  unsigned u = __float_as_uint(f);
  u = u + 0x7FFFu + ((u >> 16) & 1u);
  return (unsigned short)(u >> 16);
}

static __device__ __forceinline__ float4 fma4(float w, float4 v, float4 o) {
  o.x = fmaf(w, v.x, o.x); o.y = fmaf(w, v.y, o.y);
  o.z = fmaf(w, v.z, o.z); o.w = fmaf(w, v.w, o.w);
  return o;
}

// ---------------- K1: partial GEMMs for q (32x4096x4096) and k/v (32x4096x128) ----------------
__global__ __launch_bounds__(256) void k_proj(
    const float* __restrict__ x, const float* __restrict__ Wq,
    const float* __restrict__ Wk, const float* __restrict__ Wv,
    float* __restrict__ partq, float* __restrict__ partk, float* __restrict__ partv) {
  __shared__ __align__(16) float xs[B_][128];
  const int tid = threadIdx.x;
  const int bid = blockIdx.x;
  const bool qmode = (bid < 512);
  const int kc = qmode ? (bid >> 4) : (bid - 512);
  const int nt = qmode ? (bid & 15) : 0;

#pragma unroll
  for (int i = 0; i < 4; ++i) {
    const int j = i * 256 + tid;
    const int r = j >> 5, c4 = j & 31;
    *reinterpret_cast<float4*>(&xs[r][c4 * 4]) =
        *reinterpret_cast<const float4*>(x + (size_t)r * F_ + kc * 128 + c4 * 4);
  }
  __syncthreads();

  float acc[B_];
#pragma unroll
  for (int b = 0; b < B_; ++b) acc[b] = 0.f;

  if (qmode) {
    const float* wp = Wq + (size_t)(kc * 128) * 4096 + nt * 256 + tid;
    float w0 = wp[0], w1 = wp[4096], w2 = wp[2 * 4096], w3 = wp[3 * 4096];
    for (int fg = 0; fg < 32; ++fg) {
      const int fn = (fg + 1 < 32) ? (fg + 1) : 31;
      const float* np = wp + (size_t)(fn * 4) * 4096;
      const float n0 = np[0], n1 = np[4096], n2 = np[2 * 4096], n3 = np[3 * 4096];
#pragma unroll
      for (int b = 0; b < B_; ++b) {
        const float4 xv = *reinterpret_cast<const float4*>(&xs[b][fg * 4]);
        float a = acc[b];
        a = fmaf(xv.x, w0, a); a = fmaf(xv.y, w1, a);
        a = fmaf(xv.z, w2, a); a = fmaf(xv.w, w3, a);
        acc[b] = a;
      }
      w0 = n0; w1 = n1; w2 = n2; w3 = n3;
    }
#pragma unroll
    for (int b = 0; b < B_; ++b)
      partq[(size_t)(kc * B_ + b) * 4096 + nt * 256 + tid] = acc[b];
  } else {
    const float* wsrc = (tid < 128) ? Wk : Wv;
    const int d = tid & 127;
    const float* wp = wsrc + (size_t)(kc * 128) * 128 + d;
    float w0 = wp[0], w1 = wp[128], w2 = wp[256], w3 = wp[384];
    for (int fg = 0; fg < 32; ++fg) {
      const int fn = (fg + 1 < 32) ? (fg + 1) : 31;
      const float* np = wp + (size_t)(fn * 4) * 128;
      const float n0 = np[0], n1 = np[128], n2 = np[256], n3 = np[384];
#pragma unroll
      for (int b = 0; b < B_; ++b) {
        const float4 xv = *reinterpret_cast<const float4*>(&xs[b][fg * 4]);
        float a = acc[b];
        a = fmaf(xv.x, w0, a); a = fmaf(xv.y, w1, a);
        a = fmaf(xv.z, w2, a); a = fmaf(xv.w, w3, a);
        acc[b] = a;
      }
      w0 = n0; w1 = n1; w2 = n2; w3 = n3;
    }
    float* dst = (tid < 128) ? partk : partv;
#pragma unroll
    for (int b = 0; b < B_; ++b)
      dst[(kc * B_ + b) * 128 + d] = acc[b];
  }
}

// ---------------- K1b: reduce partials, RoPE, scale q, extra logit ----------------
__global__ __launch_bounds__(256) void k_rope(
    const float* __restrict__ partq, const float* __restrict__ partk,
    const float* __restrict__ partv, const int* __restrict__ cidx,
    float* __restrict__ qf, float* __restrict__ vf, float* __restrict__ extra) {
  const int b = blockIdx.x, tid = threadIdx.x;
  __shared__ float qs[4096];
  __shared__ float ks2[128];
  __shared__ float scs[64], scc[64];
  __shared__ float ep[H_][8];
  const int pos = cidx[b];
  if (tid < 64) {
    const float freq = expf(-(float)tid * 0.14391156831212787f); // 10000^(-tid/64)
    const float ang = (float)pos * freq;
    scs[tid] = sinf(ang);
    scc[tid] = cosf(ang);
  }
  float kvsum = 0.f;
  if (tid < 128) {
    for (int kc = 0; kc < NKC; ++kc) kvsum += partk[(kc * B_ + b) * 128 + tid];
    ks2[tid] = kvsum;
  } else {
    const int d = tid - 128;
    for (int kc = 0; kc < NKC; ++kc) kvsum += partv[(kc * B_ + b) * 128 + d];
    vf[b * 128 + d] = kvsum;
  }
  float qsum[16];
#pragma unroll
  for (int i = 0; i < 16; ++i) {
    const int n = i * 256 + tid;
    float s = 0.f;
    for (int kc = 0; kc < NKC; ++kc) s += partq[(size_t)(kc * B_ + b) * 4096 + n];
    qsum[i] = s;
    qs[n] = s;
  }
  __syncthreads();
  float qr[16];
#pragma unroll
  for (int i = 0; i < 16; ++i) {
    const int n = i * 256 + tid;
    const int d = n & 127, j = d & 63;
    const float sv = scs[j], cv2 = scc[j];
    const float a = qsum[i];
    const float p2 = qs[n ^ 64];
    qr[i] = ((d < 64) ? (a * cv2 - p2 * sv) : (a * cv2 + p2 * sv)) * SCALE;
  }
  float kr = 0.f;
  if (tid < 128) {
    const int d = tid, j = d & 63;
    const float p2 = ks2[d ^ 64];
    kr = (d < 64) ? (kvsum * scc[j] - p2 * scs[j]) : (kvsum * scc[j] + p2 * scs[j]);
  }
  __syncthreads();
#pragma unroll
  for (int i = 0; i < 16; ++i) {
    const int n = i * 256 + tid;
    qf[(size_t)b * 4096 + n] = qr[i];
    qs[n] = qr[i];
  }
  if (tid < 128) ks2[tid] = kr;
  __syncthreads();
  {
    const int h = tid >> 3, dseg = (tid & 7) * 16;
    float p = 0.f;
#pragma unroll
    for (int j = 0; j < 16; ++j) p += qs[h * 128 + dseg + j] * ks2[dseg + j];
    ep[h][tid & 7] = p;
  }
  __syncthreads();
  if (tid < 32) {
    float e = 0.f;
#pragma unroll
    for (int j = 0; j < 8; ++j) e += ep[tid][j];
    extra[b * H_ + tid] = e;
  }
}

// ---------------- K2: flash-decode chunk kernel ----------------
static __device__ __forceinline__ void stage_v(
    unsigned short (*vls)[136], const float* __restrict__ Vc,
    const float* __restrict__ vf, int b, int idx, int lbase, int tid) {
  const int r0 = tid >> 5;
  const int lc = tid & 31;
#pragma unroll
  for (int it = 0; it < 16; ++it) {
    const int d = r0 + it * 8;
    const int lb = lbase + lc * 4;
    float4 a = *reinterpret_cast<const float4*>(Vc + ((size_t)b * D_ + d) * L_ + lb);
    if ((unsigned)(idx - lb) < 4u) {
      const float vn = vf[b * D_ + d];
      a.x += (lb + 0 == idx) ? vn : 0.f;
      a.y += (lb + 1 == idx) ? vn : 0.f;
      a.z += (lb + 2 == idx) ? vn : 0.f;
      a.w += (lb + 3 == idx) ? vn : 0.f;
    }
    short4v w;
    w[0] = (short)f2bf(a.x); w[1] = (short)f2bf(a.y);
    w[2] = (short)f2bf(a.z); w[3] = (short)f2bf(a.w);
    *reinterpret_cast<short4v*>(&vls[d][lc * 4]) = w;
  }
}

__global__ __launch_bounds__(256) void k_attn(
    const float* __restrict__ Kc, const float* __restrict__ Vc,
    const float* __restrict__ qf, const float* __restrict__ vf,
    const float* __restrict__ extra, const int* __restrict__ cidx,
    float* __restrict__ mbuf, float* __restrict__ sbuf, float* __restrict__ obuf) {
  const int b = blockIdx.x, c = blockIdx.y;
  const int idx = cidx[b];
  const int l0 = c * CL;
  if (l0 > idx) return;
  const int tid = threadIdx.x;

  __shared__ __align__(16) float qls[H_][D_];
  __shared__ __align__(16) unsigned short pls[H_][CL + 8];
  __shared__ __align__(16) unsigned short vls[D_][136];
  __shared__ float red[4][H_];
  __shared__ float mls[H_];

  {
    const float4* src = reinterpret_cast<const float4*>(qf + (size_t)b * 4096);
    float4* dst = reinterpret_cast<float4*>(&qls[0][0]);
#pragma unroll
    for (int i = 0; i < 4; ++i) dst[i * 256 + tid] = src[i * 256 + tid];
  }
  stage_v(vls, Vc, vf, b, idx, l0, tid);
  __syncthreads();

  const int l = l0 + tid;
  float acc[H_];
#pragma unroll
  for (int h = 0; h < H_; ++h) acc[h] = 0.f;
  {
    const float* Kp = Kc + (size_t)b * D_ * L_ + l;
    float k0 = Kp[0], k1 = Kp[(size_t)L_], k2 = Kp[(size_t)2 * L_], k3 = Kp[(size_t)3 * L_];
    for (int dg = 0; dg < 32; ++dg) {
      const int dn = (dg + 1 < 32) ? (dg + 1) : 31;
      const float* np = Kp + (size_t)(dn * 4) * L_;
      const float n0 = np[0], n1 = np[(size_t)L_], n2 = np[(size_t)2 * L_], n3 = np[(size_t)3 * L_];
#pragma unroll
      for (int h = 0; h < H_; ++h) {
        const float4 q4 = *reinterpret_cast<const float4*>(&qls[h][dg * 4]);
        float a = acc[h];
        a = fmaf(q4.x, k0, a); a = fmaf(q4.y, k1, a);
        a = fmaf(q4.z, k2, a); a = fmaf(q4.w, k3, a);
        acc[h] = a;
      }
      k0 = n0; k1 = n1; k2 = n2; k3 = n3;
    }
  }
  if (l == idx) {
#pragma unroll
    for (int h = 0; h < H_; ++h) acc[h] += extra[b * H_ + h];
  }
  if (l > idx) {
#pragma unroll
    for (int h = 0; h < H_; ++h) acc[h] = -1e30f;
  }
  const int lane = tid & 63, wid = tid >> 6;
#pragma unroll
  for (int h = 0; h < H_; ++h) {
    float v = acc[h];
    v = fmaxf(v, __shfl_xor(v, 1, 64));
    v = fmaxf(v, __shfl_xor(v, 2, 64));
    v = fmaxf(v, __shfl_xor(v, 4, 64));
    v = fmaxf(v, __shfl_xor(v, 8, 64));
    v = fmaxf(v, __shfl_xor(v, 16, 64));
    v = fmaxf(v, __shfl_xor(v, 32, 64));
    if (lane == 0) red[wid][h] = v;
  }
  __syncthreads();
  if (tid < H_)
    mls[tid] = fmaxf(fmaxf(red[0][tid], red[1][tid]), fmaxf(red[2][tid], red[3][tid]));
  __syncthreads();
#pragma unroll
  for (int h = 0; h < H_; ++h) {
    const float p = exp2f((acc[h] - mls[h]) * LOG2E);
    acc[h] = p;
    pls[h][tid] = f2bf(p);
  }
#pragma unroll
  for (int h = 0; h < H_; ++h) {
    float v = acc[h];
    v += __shfl_xor(v, 1, 64); v += __shfl_xor(v, 2, 64);
    v += __shfl_xor(v, 4, 64); v += __shfl_xor(v, 8, 64);
    v += __shfl_xor(v, 16, 64); v += __shfl_xor(v, 32, 64);
    if (lane == 0) red[wid][h] = v;
  }
  __syncthreads();
  if (tid < H_) {
    mbuf[((size_t)b * NCH + c) * H_ + tid] = mls[tid];
    sbuf[((size_t)b * NCH + c) * H_ + tid] =
        red[0][tid] + red[1][tid] + red[2][tid] + red[3][tid];
  }

  // ---- PV via MFMA: o[h][d] = sum_l p[h][l] * V[d][l] ----
  const int mrow = lane & 15;
  const int kcol = (lane >> 4) * 8;
  f32x4 o00 = {0.f, 0.f, 0.f, 0.f}, o01 = o00, o10 = o00, o11 = o00;
#pragma unroll
  for (int pass = 0; pass < 2; ++pass) {
    if (pass == 1) {
      __syncthreads();
      stage_v(vls, Vc, vf, b, idx, l0 + 128, tid);
      __syncthreads();
    }
#pragma unroll
    for (int ks = 0; ks < 4; ++ks) {
      const int lofs = pass * 128 + ks * 32 + kcol;
      const bf16x8 a0 = *reinterpret_cast<const bf16x8*>(&pls[mrow][lofs]);
      const bf16x8 a1 = *reinterpret_cast<const bf16x8*>(&pls[16 + mrow][lofs]);
      const int vofs = ks * 32 + kcol;
      const bf16x8 b0 = *reinterpret_cast<const bf16x8*>(&vls[(wid * 2 + 0) * 16 + mrow][vofs]);
      const bf16x8 b1 = *reinterpret_cast<const bf16x8*>(&vls[(wid * 2 + 1) * 16 + mrow][vofs]);
      o00 = __builtin_amdgcn_mfma_f32_16x16x32_bf16(a0, b0, o00, 0, 0, 0);
      o01 = __builtin_amdgcn_mfma_f32_16x16x32_bf16(a0, b1, o01, 0, 0, 0);
      o10 = __builtin_amdgcn_mfma_f32_16x16x32_bf16(a1, b0, o10, 0, 0, 0);
      o11 = __builtin_amdgcn_mfma_f32_16x16x32_bf16(a1, b1, o11, 0, 0, 0);
    }
  }
  float* ob = obuf + (((size_t)b * NCH + c) * H_) * D_;
  const int rbase = (lane >> 4) * 4;
#pragma unroll
  for (int r = 0; r < 4; ++r) {
    ob[(rbase + r) * D_ + (wid * 2 + 0) * 16 + mrow] = o00[r];
    ob[(rbase + r) * D_ + (wid * 2 + 1) * 16 + mrow] = o01[r];
    ob[(16 + rbase + r) * D_ + (wid * 2 + 0) * 16 + mrow] = o10[r];
    ob[(16 + rbase + r) * D_ + (wid * 2 + 1) * 16 + mrow] = o11[r];
  }
}

// ---------------- K2b: merge chunk partials ----------------
__global__ __launch_bounds__(256) void k_combine(
    const float* __restrict__ mbuf, const float* __restrict__ sbuf,
    const float* __restrict__ obuf, const int* __restrict__ cidx,
    float* __restrict__ attn) {
  const int b = blockIdx.x, tid = threadIdx.x;
  const int nc = (cidx[b] >> 8) + 1;
  const int h = tid >> 3, ds = (tid & 7) * 16;
  float M = -1e30f;
  for (int c = 0; c < nc; ++c)
    M = fmaxf(M, mbuf[((size_t)b * NCH + c) * H_ + h]);
  float denom = 0.f;
  float4 o0 = {0, 0, 0, 0}, o1 = o0, o2 = o0, o3 = o0;
  for (int c = 0; c < nc; ++c) {
    const size_t base = ((size_t)b * NCH + c) * H_ + h;
    const float w = exp2f((mbuf[base] - M) * LOG2E);
    denom = fmaf(sbuf[base], w, denom);
    const float4* op = reinterpret_cast<const float4*>(obuf + base * D_ + ds);
    o0 = fma4(w, op[0], o0); o1 = fma4(w, op[1], o1);
    o2 = fma4(w, op[2], o2); o3 = fma4(w, op[3], o3);
  }
  const float inv = 1.f / denom;
  float4* ap = reinterpret_cast<float4*>(attn + (size_t)b * 4096 + h * D_ + ds);
  o0.x *= inv; o0.y *= inv; o0.z *= inv; o0.w *= inv;
  o1.x *= inv; o1.y *= inv; o1.z *= inv; o1.w *= inv;
  o2.x *= inv; o2.y *= inv; o2.z *= inv; o2.w *= inv;
  o3.x *= inv; o3.y *= inv; o3.z *= inv; o3.w *= inv;
  ap[0] = o0; ap[1] = o1; ap[2] = o2; ap[3] = o3;
}

// ---------------- K3: output projection partials ----------------
__global__ __launch_bounds__(256) void k_out(
    const float* __restrict__ attn, const float* __restrict__ Wo,
    float* __restrict__ parto) {
  __shared__ __align__(16) float as2[B_][128];
  const int tid = threadIdx.x;
  const int kc = blockIdx.x >> 4, ft = blockIdx.x & 15;
#pragma unroll
  for (int i = 0; i < 4; ++i) {
    const int j = i * 256 + tid;
    const int r = j >> 5, c4 = j & 31;
    *reinterpret_cast<float4*>(&as2[r][c4 * 4]) =
        *reinterpret_cast<const float4*>(attn + (size_t)r * 4096 + kc * 128 + c4 * 4);
  }
  __syncthreads();
  float acc[B_];
#pragma unroll
  for (int b = 0; b < B_; ++b) acc[b] = 0.f;
  const float* wp = Wo + (size_t)(kc * 128) * 4096 + ft * 256 + tid;
  float w0 = wp[0], w1 = wp[4096], w2 = wp[2 * 4096], w3 = wp[3 * 4096];
  for (int fg = 0; fg < 32; ++fg) {
    const int fn = (fg + 1 < 32) ? (fg + 1) : 31;
    const float* np = wp + (size_t)(fn * 4) * 4096;
    const float n0 = np[0], n1 = np[4096], n2 = np[2 * 4096], n3 = np[3 * 4096];
#pragma unroll
    for (int b = 0; b < B_; ++b) {
      const float4 xv = *reinterpret_cast<const float4*>(&as2[b][fg * 4]);
      float a = acc[b];
      a = fmaf(xv.x, w0, a); a = fmaf(xv.y, w1, a);
      a = fmaf(xv.z, w2, a); a = fmaf(xv.w, w3, a);
      acc[b] = a;
    }
    w0 = n0; w1 = n1; w2 = n2; w3 = n3;
  }
#pragma unroll
  for (int b = 0; b < B_; ++b)
    parto[(size_t)(kc * B_ + b) * 4096 + ft * 256 + tid] = acc[b];
}

__global__ __launch_bounds__(256) void k_sum(const float* __restrict__ parto,
                                             float* __restrict__ out) {
  const int n = blockIdx.x * 256 + threadIdx.x;
  float s = 0.f;
#pragma unroll
  for (int kc = 0; kc < NKC; ++kc) s += parto[(size_t)kc * 131072 + n];
  out[n] = s;
}

extern "C" void kernel_launch(void* const* d_in, const int* in_sizes, int n_in,
                              void* d_out, int out_size, void* d_ws, size_t ws_size,
                              hipStream_t stream) {
  (void)in_sizes; (void)n_in; (void)out_size; (void)ws_size;
  const float* x  = (const float*)d_in[0];
  const float* ck = (const float*)d_in[1];
  const float* cv = (const float*)d_in[2];
  const float* Wq = (const float*)d_in[3];
  const float* Wk = (const float*)d_in[4];
  const float* Wv = (const float*)d_in[5];
  const float* Wo = (const float*)d_in[6];
  const int*   ci = (const int*)d_in[7];
  float* out = (float*)d_out;
  float* ws = (float*)d_ws;

  float* partq = ws;                    // 32*32*4096 = 4,194,304
  float* partk = partq + 4194304;       // 131,072
  float* partv = partk + 131072;        // 131,072
  float* qf    = partv + 131072;        // 131,072
  float* vf    = qf + 131072;           // 4,096
  float* extra = vf + 4096;             // 1,024
  float* mbuf  = extra + 1024;          // 32,768
  float* sbuf  = mbuf + 32768;          // 32,768
  float* obuf  = sbuf + 32768;          // 4,194,304
  float* attn  = obuf + 4194304;        // 131,072
  float* parto = attn + 131072;         // 4,194,304   (total ~52.7 MB)

  k_proj<<<dim3(544), dim3(256), 0, stream>>>(x, Wq, Wk, Wv, partq, partk, partv);
  k_rope<<<dim3(32), dim3(256), 0, stream>>>(partq, partk, partv, ci, qf, vf, extra);
  k_attn<<<dim3(32, 32), dim3(256), 0, stream>>>(ck, cv, qf, vf, extra, ci, mbuf, sbuf, obuf);
  k_combine<<<dim3(32), dim3(256), 0, stream>>>(mbuf, sbuf, obuf, ci, attn);
  k_out<<<dim3(512), dim3(256), 0, stream>>>(attn, Wo, parto);
  k_sum<<<dim3(512), dim3(256), 0, stream>>>(parto, out);
}